// Round 5
// baseline (312.308 us; speedup 1.0000x reference)
//
#include <hip/hip_runtime.h>

// Problem constants (fixed by setup_inputs)
#define Bb 32
#define Cc 4
#define Hh 512
#define Ww 512
#define Tt 64
#define HW (Hh * Ww)                          // 262144
#define NTOT ((long long)Bb * Cc * Hh * Ww)   // 33,554,432 floats per tensor
#define QTOT (Bb * Cc * HW / 4)               // 8,388,608 float4 granules

// Main kernel: 4096 blocks x 256 threads, 8 granules per thread,
// hand-pipelined: 24 loads in flight per thread via inline asm.
#define GRID2 4096
#define THREADS2 (GRID2 * 256)                // 1,048,576 = 2^20
#define KPT 8                                 // QTOT / THREADS2

// ws layout:
//   [0 .. GRID2*8)                  : double partials[GRID2]   (32 KiB)
//   [65536 .. 65536 + B*H*8*8)      : uint64 rowmask[B*H][8]   (1 MiB)
#define ROWMASK_OFF 65536

typedef float f32x4 __attribute__((ext_vector_type(4)));

// ---------------------------------------------------------------------------
// Kernel 1: build per-(b,h) column bitmask (512 bits = 8 u64 words per row).
// ---------------------------------------------------------------------------
__global__ __launch_bounds__(256) void build_rowmask_kernel(
    const float* __restrict__ pos,                // [B, T, 2] (x, y)
    unsigned long long* __restrict__ rowmask)     // [B*H][8]
{
    int row = blockIdx.x * 256 + threadIdx.x;     // 0 .. B*H-1
    if (row >= Bb * Hh) return;
    int b = row >> 9;     // row / 512
    int h = row & 511;

    unsigned long long m[8];
#pragma unroll
    for (int i = 0; i < 8; ++i) m[i] = 0ull;

    const float* p = pos + (size_t)b * Tt * 2;
    for (int t = 0; t < Tt; ++t) {
        float x = p[2 * t + 0];
        float y = p[2 * t + 1];
        if (!(x > 0.0f && y > 0.0f)) continue;
        int xp = (int)floorf(x * (float)Ww);
        int yp = (int)floorf(y * (float)Hh);
        if (h < yp - 5 || h >= yp + 5) continue;  // row not covered by this box
        int xlo = xp - 5; if (xlo < 0) xlo = 0;
        int xhi = xp + 5; if (xhi > Ww) xhi = Ww;
        if (xlo >= xhi) continue;
        int w0 = xlo >> 6;
        int w1 = (xhi - 1) >> 6;
        for (int wd = w0; wd <= w1; ++wd) {
            int lo = xlo - (wd << 6); if (lo < 0) lo = 0;
            int hi = xhi - (wd << 6); if (hi > 64) hi = 64;
            m[wd] |= (((1ull << (hi - lo)) - 1ull) << lo);
        }
    }

    unsigned long long* out = rowmask + (size_t)row * 8;
#pragma unroll
    for (int i = 0; i < 8; ++i) out[i] = m[i];
}

// ---------------------------------------------------------------------------
// Kernel 2: weighted squared-difference reduction.
// Flat traversal (granule = one float4 of one channel; the 1+3*mask weight is
// channel-independent so per-channel masking is identical math).
// Index decode (quads): wq bits[0:7) h bits[7:16) c bits[16:18) b bits[18:24)
//
// Because THREADS2 = 2^20, the per-k address deltas are compile-time consts:
//   vo[k] = tid*16 + k*2^24          (tensor byte offset)
//   ro[k] = ro0   + k*131072         (rowmask byte offset; b advances by 4/k)
//   sh    = (tid & 15) * 4           (identical for all k)
// Inline-asm pipeline: 8 rowmask dwordx2 + 16 tensor dwordx4 issued
// back-to-back, consumed under counted s_waitcnt vmcnt(14-2k);
// sched_barrier(0) after each wait (rule #18).
// ---------------------------------------------------------------------------
__global__ __launch_bounds__(256, 4) void weighted_sq_sum_kernel(
    const float* __restrict__ pred,
    const float* __restrict__ targ,
    const unsigned long long* __restrict__ rowmask,
    double* __restrict__ partials)
{
    const int tid = blockIdx.x * 256 + (int)threadIdx.x;   // 0 .. THREADS2-1

    const unsigned vo0 = (unsigned)tid * 16u;
    const unsigned ro0 =
        (((unsigned)(tid >> 18) * 512u + (unsigned)((tid >> 7) & 511)) * 8u
         + (unsigned)((tid >> 4) & 7)) * 8u;
    const unsigned sh = (unsigned)((tid & 15) << 2);

    unsigned long long rm[KPT];
    f32x4 pv[KPT], tv[KPT];

    // Issue phase: 24 vector loads, no waits in between.
#pragma unroll
    for (int k = 0; k < KPT; ++k) {
        unsigned ro = ro0 + (unsigned)k * 131072u;
        asm volatile("global_load_dwordx2 %0, %1, %2"
                     : "=&v"(rm[k]) : "v"(ro), "s"(rowmask));
    }
#pragma unroll
    for (int k = 0; k < KPT; ++k) {
        unsigned vo = vo0 + (unsigned)k * 16777216u;
        asm volatile("global_load_dwordx4 %0, %1, %2"
                     : "=&v"(pv[k]) : "v"(vo), "s"(pred));
        asm volatile("global_load_dwordx4 %0, %1, %2"
                     : "=&v"(tv[k]) : "v"(vo), "s"(targ));
    }

    double acc = 0.0;

    // Consume phase: in-order drain; counted vmcnt keeps later loads in flight.
#define CONSUME(k, n)                                                         \
    {                                                                         \
        asm volatile("s_waitcnt vmcnt(" #n ")" ::: "memory");                 \
        __builtin_amdgcn_sched_barrier(0);                                    \
        f32x4 a = pv[k], t = tv[k];                                           \
        float dx = a.x - t.x, dy = a.y - t.y, dz = a.z - t.z, dw = a.w - t.w; \
        float sx = dx * dx, sy = dy * dy, sz = dz * dz, sw = dw * dw;         \
        unsigned bits = (unsigned)((rm[k] >> sh) & 0xFull);                   \
        float tot  = sx + sy + sz + sw;                                       \
        float msum = (bits & 1u ? sx : 0.f) + (bits & 2u ? sy : 0.f) +        \
                     (bits & 4u ? sz : 0.f) + (bits & 8u ? sw : 0.f);         \
        acc += (double)tot + 3.0 * (double)msum;                              \
    }

    CONSUME(0, 14)
    CONSUME(1, 12)
    CONSUME(2, 10)
    CONSUME(3, 8)
    CONSUME(4, 6)
    CONSUME(5, 4)
    CONSUME(6, 2)
    CONSUME(7, 0)
#undef CONSUME

    // wave (64-lane) reduction
#pragma unroll
    for (int off = 32; off > 0; off >>= 1)
        acc += __shfl_down(acc, off, 64);

    __shared__ double lsum[4];
    int lane = threadIdx.x & 63;
    int wid  = threadIdx.x >> 6;
    if (lane == 0) lsum[wid] = acc;
    __syncthreads();
    if (threadIdx.x == 0)
        partials[blockIdx.x] = lsum[0] + lsum[1] + lsum[2] + lsum[3];
}

// ---------------------------------------------------------------------------
// Kernel 3: reduce 4096 partials, scale by 1/N, write scalar fp32 output.
// ---------------------------------------------------------------------------
__global__ __launch_bounds__(256) void final_reduce_kernel(
    const double* __restrict__ partials, float* __restrict__ out)
{
    double v = 0.0;
    for (int i = threadIdx.x; i < GRID2; i += 256) v += partials[i];
#pragma unroll
    for (int off = 32; off > 0; off >>= 1)
        v += __shfl_down(v, off, 64);
    __shared__ double lsum[4];
    int lane = threadIdx.x & 63;
    int wid  = threadIdx.x >> 6;
    if (lane == 0) lsum[wid] = v;
    __syncthreads();
    if (threadIdx.x == 0)
        out[0] = (float)((lsum[0] + lsum[1] + lsum[2] + lsum[3]) * (1.0 / (double)NTOT));
}

extern "C" void kernel_launch(void* const* d_in, const int* in_sizes, int n_in,
                              void* d_out, int out_size, void* d_ws, size_t ws_size,
                              hipStream_t stream) {
    const float* pred = (const float*)d_in[0];   // [32,4,512,512] f32
    const float* targ = (const float*)d_in[1];   // [32,4,512,512] f32
    // d_in[2] = text_tokens (unused by the loss)
    const float* pos  = (const float*)d_in[3];   // [32,64,2] f32

    double* partials = (double*)d_ws;
    unsigned long long* rowmask =
        (unsigned long long*)((char*)d_ws + ROWMASK_OFF);
    float* out = (float*)d_out;

    // 1) per-row column bitmasks: B*H = 16384 rows
    build_rowmask_kernel<<<(Bb * Hh + 255) / 256, 256, 0, stream>>>(pos, rowmask);

    // 2) main reduction: inline-asm deep load pipeline
    weighted_sq_sum_kernel<<<GRID2, 256, 0, stream>>>(pred, targ, rowmask, partials);

    // 3) finalize
    final_reduce_kernel<<<1, 256, 0, stream>>>(partials, out);
}

// Round 6
// 289.499 us; speedup vs baseline: 1.0788x; 1.0788x over previous
//
#include <hip/hip_runtime.h>

// Problem constants (fixed by setup_inputs)
#define Bb 32
#define Cc 4
#define Hh 512
#define Ww 512
#define Tt 64
#define HW (Hh * Ww)            // 262144
#define NTOT ((long long)Bb * Cc * Hh * Ww)  // 33,554,432
#define NQUAD (Bb * HW / 4)     // 2,097,152 quads (4 pixels x 4 channels each)

// Main-kernel grid: 2048 blocks x 256 threads, grid-stride, 4 quads/thread.
#define GRID2 2048
#define ITER2 (NQUAD / (GRID2 * 256))   // = 4 exactly

// ws layout:
//   [0 .. GRID2*8)                  : double partials[GRID2]   (16 KiB)
//   [65536 .. 65536 + B*H*8*8)      : uint64 rowmask[B*H][8]   (1 MiB)
#define ROWMASK_OFF 65536

// ---------------------------------------------------------------------------
// Kernel 1: build per-(b,h) column bitmask (512 bits = 8 u64 words per row).
// One thread per image row. Every word is written, so no zero-init of ws needed.
// ---------------------------------------------------------------------------
__global__ __launch_bounds__(256) void build_rowmask_kernel(
    const float* __restrict__ pos,                // [B, T, 2] (x, y)
    unsigned long long* __restrict__ rowmask)     // [B*H][8]
{
    int row = blockIdx.x * 256 + threadIdx.x;     // 0 .. B*H-1
    if (row >= Bb * Hh) return;
    int b = row >> 9;     // row / 512
    int h = row & 511;

    unsigned long long m[8];
#pragma unroll
    for (int i = 0; i < 8; ++i) m[i] = 0ull;

    const float* p = pos + (size_t)b * Tt * 2;
    for (int t = 0; t < Tt; ++t) {
        float x = p[2 * t + 0];
        float y = p[2 * t + 1];
        if (!(x > 0.0f && y > 0.0f)) continue;
        int xp = (int)floorf(x * (float)Ww);
        int yp = (int)floorf(y * (float)Hh);
        if (h < yp - 5 || h >= yp + 5) continue;  // row not covered by this box
        int xlo = xp - 5; if (xlo < 0) xlo = 0;
        int xhi = xp + 5; if (xhi > Ww) xhi = Ww;
        if (xlo >= xhi) continue;
        int w0 = xlo >> 6;
        int w1 = (xhi - 1) >> 6;
        for (int wd = w0; wd <= w1; ++wd) {
            int lo = xlo - (wd << 6); if (lo < 0) lo = 0;
            int hi = xhi - (wd << 6); if (hi > 64) hi = 64;
            // hi - lo <= 10 < 64, shift is safe
            m[wd] |= (((1ull << (hi - lo)) - 1ull) << lo);
        }
    }

    unsigned long long* out = rowmask + (size_t)row * 8;
#pragma unroll
    for (int i = 0; i < 8; ++i) out[i] = m[i];
}

// ---------------------------------------------------------------------------
// Kernel 2: main weighted squared-difference reduction.
// Grid-stride version: 2048 blocks (8 blocks/CU resident), each thread owns
// 4 quads (one quad = 4 consecutive pixels across all 4 channels).
// Best-measured schedule of the session (k2 ~95 us = ~2.82 TB/s effective
// read, ~90% of the externally-anchored per-direction fabric read ceiling).
// ---------------------------------------------------------------------------
__global__ __launch_bounds__(256, 8) void weighted_sq_sum_kernel(
    const float* __restrict__ pred,
    const float* __restrict__ targ,
    const unsigned long long* __restrict__ rowmask,
    double* __restrict__ partials)
{
    const int tid0 = blockIdx.x * 256 + threadIdx.x;   // 0 .. 524287
    const int PS = HW / 4;                             // plane stride in float4s

    double acc = 0.0;
#pragma unroll
    for (int it = 0; it < ITER2; ++it) {
        int gid = tid0 + it * (GRID2 * 256);    // quad id, exact cover
        int b   = gid >> 16;                    // / (HW/4 = 65536)
        int rem = gid & 65535;
        int h   = rem >> 7;                     // / (W/4 = 128)
        int w   = (rem & 127) << 2;

        size_t base = (size_t)b * (Cc * HW) + (size_t)h * Ww + (size_t)w;
        const float4* p4 = (const float4*)(pred + base);
        const float4* t4 = (const float4*)(targ + base);

        // mask word for this 64-column granule; 4 bits for this quad
        unsigned long long word = rowmask[((size_t)b * Hh + h) * 8 + (w >> 6)];
        unsigned bits = (unsigned)((word >> (w & 63)) & 0xFull);

        float sx = 0.f, sy = 0.f, sz = 0.f, sw = 0.f;
#pragma unroll
        for (int c = 0; c < Cc; ++c) {
            float4 a = p4[(size_t)c * PS];
            float4 t = t4[(size_t)c * PS];
            float dx = a.x - t.x, dy = a.y - t.y, dz = a.z - t.z, dw = a.w - t.w;
            sx += dx * dx; sy += dy * dy; sz += dz * dz; sw += dw * dw;
        }

        float tot  = sx + sy + sz + sw;
        float msum = (bits & 1u ? sx : 0.f) + (bits & 2u ? sy : 0.f) +
                     (bits & 4u ? sz : 0.f) + (bits & 8u ? sw : 0.f);
        acc += (double)tot + 3.0 * (double)msum;
    }

    // wave (64-lane) reduction
#pragma unroll
    for (int off = 32; off > 0; off >>= 1)
        acc += __shfl_down(acc, off, 64);

    __shared__ double lsum[4];
    int lane = threadIdx.x & 63;
    int wid  = threadIdx.x >> 6;
    if (lane == 0) lsum[wid] = acc;
    __syncthreads();
    if (threadIdx.x == 0)
        partials[blockIdx.x] = lsum[0] + lsum[1] + lsum[2] + lsum[3];
}

// ---------------------------------------------------------------------------
// Kernel 3: reduce 2048 partials, scale by 1/N, write scalar fp32 output.
// ---------------------------------------------------------------------------
__global__ __launch_bounds__(256) void final_reduce_kernel(
    const double* __restrict__ partials, float* __restrict__ out)
{
    double v = 0.0;
    for (int i = threadIdx.x; i < GRID2; i += 256) v += partials[i];
#pragma unroll
    for (int off = 32; off > 0; off >>= 1)
        v += __shfl_down(v, off, 64);
    __shared__ double lsum[4];
    int lane = threadIdx.x & 63;
    int wid  = threadIdx.x >> 6;
    if (lane == 0) lsum[wid] = v;
    __syncthreads();
    if (threadIdx.x == 0)
        out[0] = (float)((lsum[0] + lsum[1] + lsum[2] + lsum[3]) * (1.0 / (double)NTOT));
}

extern "C" void kernel_launch(void* const* d_in, const int* in_sizes, int n_in,
                              void* d_out, int out_size, void* d_ws, size_t ws_size,
                              hipStream_t stream) {
    const float* pred = (const float*)d_in[0];   // [32,4,512,512] f32
    const float* targ = (const float*)d_in[1];   // [32,4,512,512] f32
    // d_in[2] = text_tokens (unused by the loss)
    const float* pos  = (const float*)d_in[3];   // [32,64,2] f32

    double* partials = (double*)d_ws;
    unsigned long long* rowmask =
        (unsigned long long*)((char*)d_ws + ROWMASK_OFF);
    float* out = (float*)d_out;

    // 1) per-row column bitmasks: B*H = 16384 rows
    build_rowmask_kernel<<<(Bb * Hh + 255) / 256, 256, 0, stream>>>(pos, rowmask);

    // 2) main reduction: 2048 blocks x 256 threads, 4 quads/thread, exact cover
    weighted_sq_sum_kernel<<<GRID2, 256, 0, stream>>>(pred, targ, rowmask, partials);

    // 3) finalize
    final_reduce_kernel<<<1, 256, 0, stream>>>(partials, out);
}